// Round 5
// baseline (532.760 us; speedup 1.0000x reference)
//
#include <hip/hip_runtime.h>
#include <hip/hip_bf16.h>
#include <math.h>

#define T_TOK 1024
#define HDIM  2048
#define NEXP  8
#define IDIM  1408
#define ISH   2816
#define ROW_CAP 3072
#define ROWS_ALL 4096
#define MOE_TILES 24
#define NT_TOT 32
#define ATILE (128*64)   // one A LDS buffer (bf16 elems)

typedef __attribute__((ext_vector_type(8))) short bf16x8;
typedef __attribute__((ext_vector_type(4))) float f32x4;

static __device__ __forceinline__ unsigned short f2bf(float f) {
  __hip_bfloat16 h = __float2bfloat16(f);   // RTNE
  return __builtin_bit_cast(unsigned short, h);
}

static __device__ __forceinline__ bf16x8 cvt8(float4 a, float4 b) {
  union { unsigned short us[8]; bf16x8 v; } r;
  r.us[0]=f2bf(a.x); r.us[1]=f2bf(a.y); r.us[2]=f2bf(a.z); r.us[3]=f2bf(a.w);
  r.us[4]=f2bf(b.x); r.us[5]=f2bf(b.y); r.us[6]=f2bf(b.z); r.us[7]=f2bf(b.w);
  return r.v;
}

// ---------------- router ----------------
__global__ __launch_bounds__(256) void router_kernel(
    const float* __restrict__ x, const float* __restrict__ rw,
    float* __restrict__ logits_out, int* __restrict__ selk, float* __restrict__ cwk)
{
  int t = blockIdx.x;
  int tid = threadIdx.x;
  float part[NEXP];
  const float* xr = x + (size_t)t * HDIM + tid * 8;
  float4 xa = *reinterpret_cast<const float4*>(xr);
  float4 xb = *reinterpret_cast<const float4*>(xr + 4);
  for (int e = 0; e < NEXP; ++e) {
    const float* wp = rw + (size_t)e * HDIM + tid * 8;
    float4 wa = *reinterpret_cast<const float4*>(wp);
    float4 wb = *reinterpret_cast<const float4*>(wp + 4);
    part[e] = xa.x*wa.x + xa.y*wa.y + xa.z*wa.z + xa.w*wa.w
            + xb.x*wb.x + xb.y*wb.y + xb.z*wb.z + xb.w*wb.w;
  }
  for (int e = 0; e < NEXP; ++e)
    for (int off = 32; off; off >>= 1)
      part[e] += __shfl_xor(part[e], off, 64);
  __shared__ float sums[4][NEXP];
  int wid = tid >> 6, lane = tid & 63;
  if (lane == 0) for (int e = 0; e < NEXP; ++e) sums[wid][e] = part[e];
  __syncthreads();
  if (tid == 0) {
    float lg[NEXP];
    for (int e = 0; e < NEXP; ++e) lg[e] = sums[0][e] + sums[1][e] + sums[2][e] + sums[3][e];
    float mx = lg[0];
    for (int e = 1; e < NEXP; ++e) mx = fmaxf(mx, lg[e]);
    float p[NEXP], s = 0.f;
    for (int e = 0; e < NEXP; ++e) { p[e] = expf(lg[e] - mx); s += p[e]; }
    for (int e = 0; e < NEXP; ++e) p[e] /= s;
    int i1 = 0;
    for (int e = 1; e < NEXP; ++e) if (lg[e] > lg[i1]) i1 = e;
    int i2 = -1;
    for (int e = 0; e < NEXP; ++e) { if (e == i1) continue; if (i2 < 0 || lg[e] > lg[i2]) i2 = e; }
    float denom = p[i1] + p[i2] + 1e-6f;
    selk[t*2] = i1; selk[t*2+1] = i2;
    cwk[t*2] = p[i1] / denom; cwk[t*2+1] = p[i2] / denom;
    for (int e = 0; e < NEXP; ++e) logits_out[t * NEXP + e] = lg[e];
  }
}

// ---------------- plan ----------------
__global__ __launch_bounds__(512) void plan_kernel(
    const int* __restrict__ selk, const float* __restrict__ cwk,
    int* __restrict__ rowidx, int* __restrict__ tok_of_row,
    float* __restrict__ rowwgt, int* __restrict__ tile_tab)
{
  __shared__ int cnt[NEXP];
  __shared__ int seg[NEXP];
  int tid = threadIdx.x;
  int w = tid >> 6, lane = tid & 63;
  for (int i = tid; i < ROW_CAP; i += 512) { tok_of_row[i] = -1; rowwgt[i] = 0.f; }
  for (int i = tid; i < T_TOK; i += 512) { tok_of_row[ROW_CAP + i] = i; rowwgt[ROW_CAP + i] = 1.f; }
  int total = 0;
  for (int base = 0; base < 2 * T_TOK; base += 64) {
    unsigned long long m = __ballot(selk[base + lane] == w);
    total += __popcll(m);
  }
  if (lane == 0) cnt[w] = total;
  __syncthreads();
  if (tid == 0) {
    int s = 0;
    for (int e = 0; e < NEXP; ++e) { seg[e] = s; s += (cnt[e] + 127) & ~127; }
  }
  __syncthreads();
  int run = seg[w];
  for (int base = 0; base < 2 * T_TOK; base += 64) {
    int i = base + lane;
    bool f = selk[i] == w;
    unsigned long long m = __ballot(f);
    if (f) {
      int r = run + __popcll(m & ((1ull << lane) - 1ull));
      rowidx[i] = r;
      tok_of_row[r] = i >> 1;
      rowwgt[r] = cwk[i];
    }
    run += __popcll(m);
  }
  __syncthreads();
  if (tid < NT_TOT) {
    int e = -1, valid = 0;
    if (tid < MOE_TILES) {
      int base = tid * 128;
      for (int k = 0; k < NEXP; ++k) {
        int s0 = seg[k], s1 = s0 + ((cnt[k] + 127) & ~127);
        if (base >= s0 && base < s1) {
          e = k;
          valid = cnt[k] - (base - s0);
          if (valid > 128) valid = 128;
          if (valid < 0) valid = 0;
        }
      }
    } else { e = 0; valid = 128; }
    tile_tab[tid*2] = e;
    tile_tab[tid*2+1] = valid;
  }
}

// ---------------- gather ----------------
__global__ __launch_bounds__(256) void gather_kernel(
    const float* __restrict__ x, const int* __restrict__ tok_of_row,
    unsigned short* __restrict__ xg)
{
  int r = blockIdx.x;
  int tid = threadIdx.x;
  int tok = tok_of_row[r];
  unsigned short* dst = xg + (size_t)r * HDIM + tid * 8;
  union { unsigned short us[8]; uint4 q; } p;
  if (tok < 0) {
    p.q = uint4{0, 0, 0, 0};
  } else {
    const float* src = x + (size_t)tok * HDIM + tid * 8;
    float4 a = *reinterpret_cast<const float4*>(src);
    float4 b = *reinterpret_cast<const float4*>(src + 4);
    p.us[0]=f2bf(a.x); p.us[1]=f2bf(a.y); p.us[2]=f2bf(a.z); p.us[3]=f2bf(a.w);
    p.us[4]=f2bf(b.x); p.us[5]=f2bf(b.y); p.us[6]=f2bf(b.z); p.us[7]=f2bf(b.w);
  }
  *reinterpret_cast<uint4*>(dst) = p.q;
}

// ---- A stage: 128x64 bf16 tile, 4 glds per wave, XOR-swizzled global source ----
static __device__ __forceinline__ void stage_a3(
    const unsigned short* __restrict__ abase, size_t lda, int k0,
    unsigned short* As, int wid, int lane)
{
  #pragma unroll
  for (int j = 0; j < 4; ++j) {
    int row = j * 32 + wid * 8 + (lane >> 3);
    int col = ((lane & 7) ^ (row & 7)) << 3;
    const unsigned short* src = abase + (size_t)row * lda + k0 + col;
    unsigned short* dst = &As[(j * 32 + wid * 8) * 64];   // wave-uniform
    __builtin_amdgcn_global_load_lds(
        (const __attribute__((address_space(1))) void*)src,
        (__attribute__((address_space(3))) void*)dst, 16, 0, 0);
  }
}

struct BStage2 { float4 g0, g1, g2, g3, u0, u1, u2, u3; };
struct BStage1 { float4 b0, b1, b2, b3; };

static __device__ __forceinline__ void loadB2(
    const float* __restrict__ pg, const float* __restrict__ pu, int k, BStage2& s)
{
  s.g0 = *reinterpret_cast<const float4*>(pg + k);
  s.g1 = *reinterpret_cast<const float4*>(pg + k + 4);
  s.g2 = *reinterpret_cast<const float4*>(pg + k + 32);
  s.g3 = *reinterpret_cast<const float4*>(pg + k + 36);
  s.u0 = *reinterpret_cast<const float4*>(pu + k);
  s.u1 = *reinterpret_cast<const float4*>(pu + k + 4);
  s.u2 = *reinterpret_cast<const float4*>(pu + k + 32);
  s.u3 = *reinterpret_cast<const float4*>(pu + k + 36);
}

static __device__ __forceinline__ void loadB1(
    const float* __restrict__ pb, int k, BStage1& s)
{
  s.b0 = *reinterpret_cast<const float4*>(pb + k);
  s.b1 = *reinterpret_cast<const float4*>(pb + k + 4);
  s.b2 = *reinterpret_cast<const float4*>(pb + k + 32);
  s.b3 = *reinterpret_cast<const float4*>(pb + k + 36);
}

static __device__ __forceinline__ void stepGU(
    const BStage2& s, const unsigned short* Abuf,
    int wr, int fr, int fq8, f32x4* accg, f32x4* accu)
{
  bf16x8 bg0 = cvt8(s.g0, s.g1), bg1 = cvt8(s.g2, s.g3);
  bf16x8 bu0 = cvt8(s.u0, s.u1), bu1 = cvt8(s.u2, s.u3);
  #pragma unroll
  for (int kk = 0; kk < 2; ++kk) {
    bf16x8 a[4];
    #pragma unroll
    for (int m = 0; m < 4; ++m) {
      int row = wr * 64 + m * 16 + fr;
      a[m] = *reinterpret_cast<const bf16x8*>(
          &Abuf[row * 64 + ((kk * 32 + fq8) ^ ((row & 7) << 3))]);
    }
    bf16x8 bg = kk ? bg1 : bg0;
    bf16x8 bu = kk ? bu1 : bu0;
    #pragma unroll
    for (int m = 0; m < 4; ++m) {
      accg[m] = __builtin_amdgcn_mfma_f32_16x16x32_bf16(a[m], bg, accg[m], 0, 0, 0);
      accu[m] = __builtin_amdgcn_mfma_f32_16x16x32_bf16(a[m], bu, accu[m], 0, 0, 0);
    }
  }
}

static __device__ __forceinline__ void stepDN(
    const BStage1& s, const unsigned short* Abuf,
    int wr, int fr, int fq8, f32x4* acc)
{
  bf16x8 b0 = cvt8(s.b0, s.b1), b1 = cvt8(s.b2, s.b3);
  #pragma unroll
  for (int kk = 0; kk < 2; ++kk) {
    bf16x8 a[4];
    #pragma unroll
    for (int m = 0; m < 4; ++m) {
      int row = wr * 64 + m * 16 + fr;
      a[m] = *reinterpret_cast<const bf16x8*>(
          &Abuf[row * 64 + ((kk * 32 + fq8) ^ ((row & 7) << 3))]);
    }
    bf16x8 b = kk ? b1 : b0;
    #pragma unroll
    for (int m = 0; m < 4; ++m)
      acc[m] = __builtin_amdgcn_mfma_f32_16x16x32_bf16(a[m], b, acc[m], 0, 0, 0);
  }
}

#define WAIT_BARRIER(N) do { \
    asm volatile("s_waitcnt vmcnt(" #N ")" ::: "memory"); \
    __builtin_amdgcn_s_barrier(); \
    __builtin_amdgcn_sched_barrier(0); \
  } while (0)

// ---------------- grouped gate+up SwiGLU: B direct-to-reg, A triple-buffered LDS ----------------
__global__ __launch_bounds__(256) void gu_kernel(
    const unsigned short* __restrict__ xg,
    const float* __restrict__ w_gate, const float* __restrict__ w_up,
    const float* __restrict__ sw_gate, const float* __restrict__ sw_up,
    const float* __restrict__ rowwgt, const int* __restrict__ tile_tab,
    unsigned short* __restrict__ hg, unsigned short* __restrict__ hsh)
{
  // bijective XCD chunk swizzle: nwg = 1760 = 8 * 220, mt-fastest
  int bid = blockIdx.x;
  int lb = (bid & 7) * 220 + (bid >> 3);
  int mt, nt;
  if (lb < MOE_TILES * 44) { mt = lb % MOE_TILES; nt = lb / MOE_TILES; }
  else { int s = lb - MOE_TILES * 44; mt = MOE_TILES + (s & 7); nt = s >> 3; }

  int e = tile_tab[mt*2], valid = tile_tab[mt*2+1];
  if (valid <= 0) return;
  bool sh = mt >= MOE_TILES;
  int m0 = mt * 128, n0 = nt * 32;
  const float *wg, *wu; unsigned short* hout; int ldo;
  if (sh) { wg = sw_gate; wu = sw_up; hout = hsh + (size_t)(m0 - ROW_CAP) * ISH; ldo = ISH; }
  else {
    size_t wo = (size_t)e * IDIM * HDIM;
    wg = w_gate + wo; wu = w_up + wo;
    hout = hg + (size_t)m0 * IDIM; ldo = IDIM;
  }

  __shared__ unsigned short As[3 * ATILE];   // 48 KB

  int tid = threadIdx.x, wid = tid >> 6, lane = tid & 63;
  int wr = wid >> 1, wc = wid & 1;
  int fr = lane & 15, fq8 = (lane >> 4) << 3;

  f32x4 accg[4] = {};
  f32x4 accu[4] = {};

  int col = n0 + wc * 16 + fr;
  const float* pg_ = wg + (size_t)col * HDIM + fq8;
  const float* pu_ = wu + (size_t)col * HDIM + fq8;
  const unsigned short* abase = xg + (size_t)m0 * HDIM;

  BStage2 st0, st1;
  stage_a3(abase, HDIM, 0, As, wid, lane);
  loadB2(pg_, pu_, 0, st0);

  int use = 0, fill = 1;
  const int NK = HDIM / 64;     // 32, even
  for (int t = 0; t < NK; t += 2) {
    {
      int k1 = (t + 1 < NK) ? (t + 1) * 64 : 0;
      stage_a3(abase, HDIM, k1, As + fill * ATILE, wid, lane);
      loadB2(pg_, pu_, k1, st1);
      WAIT_BARRIER(12);
      stepGU(st0, As + use * ATILE, wr, fr, fq8, accg, accu);
      int nu = fill, nf = 3 - use - fill; use = nu; fill = nf;
    }
    {
      int k1 = (t + 2 < NK) ? (t + 2) * 64 : 0;
      stage_a3(abase, HDIM, k1, As + fill * ATILE, wid, lane);
      loadB2(pg_, pu_, k1, st0);
      WAIT_BARRIER(12);
      stepGU(st1, As + use * ATILE, wr, fr, fq8, accg, accu);
      int nu = fill, nf = 3 - use - fill; use = nu; fill = nf;
    }
  }

  int fq = lane >> 4;
  #pragma unroll
  for (int m = 0; m < 4; ++m)
    #pragma unroll
    for (int j = 0; j < 4; ++j) {
      int grow = wr * 64 + m * 16 + fq * 4 + j;
      float wv = rowwgt[m0 + grow];
      float g = accg[m][j], u = accu[m][j];
      float hv = g / (1.f + __expf(-g)) * u * wv;
      hout[(size_t)grow * ldo + col] = f2bf(hv);
    }
}

// ---------------- grouped down-proj: same structure, single B matrix ----------------
__global__ __launch_bounds__(256) void dn_kernel(
    const unsigned short* __restrict__ hg, const unsigned short* __restrict__ hsh,
    const float* __restrict__ w_down, const float* __restrict__ sw_down,
    const int* __restrict__ tile_tab,
    float* __restrict__ ydn, float* __restrict__ outf)
{
  // bijective XCD chunk swizzle: nwg = 2048 = 8 * 256, mt-fastest
  int bid = blockIdx.x;
  int lb = (bid & 7) * 256 + (bid >> 3);
  int mt, nt;
  if (lb < MOE_TILES * 64) { mt = lb % MOE_TILES; nt = lb / MOE_TILES; }
  else { int s = lb - MOE_TILES * 64; mt = MOE_TILES + (s & 7); nt = s >> 3; }

  int e = tile_tab[mt*2], valid = tile_tab[mt*2+1];
  if (valid <= 0) return;
  bool sh = mt >= MOE_TILES;
  int m0 = mt * 128, n0 = nt * 32;
  const unsigned short* abase; const float* bbase; int K; float* obase;
  if (sh) { abase = hsh + (size_t)(m0 - ROW_CAP) * ISH; K = ISH; bbase = sw_down; obase = outf + (size_t)(m0 - ROW_CAP) * HDIM; }
  else { abase = hg + (size_t)m0 * IDIM; K = IDIM; bbase = w_down + (size_t)e * HDIM * IDIM; obase = ydn + (size_t)m0 * HDIM; }

  __shared__ unsigned short As[3 * ATILE];   // 48 KB

  int tid = threadIdx.x, wid = tid >> 6, lane = tid & 63;
  int wr = wid >> 1, wc = wid & 1;
  int fr = lane & 15, fq8 = (lane >> 4) << 3;

  f32x4 acc[4] = {};

  int col = n0 + wc * 16 + fr;
  const float* pb_ = bbase + (size_t)col * K + fq8;

  BStage1 st0, st1;
  stage_a3(abase, K, 0, As, wid, lane);
  loadB1(pb_, 0, st0);

  int use = 0, fill = 1;
  const int NK = K / 64;        // 22 or 44, even
  for (int t = 0; t < NK; t += 2) {
    {
      int k1 = (t + 1 < NK) ? (t + 1) * 64 : 0;
      stage_a3(abase, K, k1, As + fill * ATILE, wid, lane);
      loadB1(pb_, k1, st1);
      WAIT_BARRIER(8);
      stepDN(st0, As + use * ATILE, wr, fr, fq8, acc);
      int nu = fill, nf = 3 - use - fill; use = nu; fill = nf;
    }
    {
      int k1 = (t + 2 < NK) ? (t + 2) * 64 : 0;
      stage_a3(abase, K, k1, As + fill * ATILE, wid, lane);
      loadB1(pb_, k1, st0);
      WAIT_BARRIER(8);
      stepDN(st1, As + use * ATILE, wr, fr, fq8, acc);
      int nu = fill, nf = 3 - use - fill; use = nu; fill = nf;
    }
  }

  int fq = lane >> 4;
  #pragma unroll
  for (int m = 0; m < 4; ++m)
    #pragma unroll
    for (int j = 0; j < 4; ++j) {
      int grow = wr * 64 + m * 16 + fq * 4 + j;
      obase[(size_t)grow * HDIM + col] = acc[m][j];
    }
}

// ---------------- combine ----------------
__global__ __launch_bounds__(256) void combine_kernel(
    const float* __restrict__ ydn, const int* __restrict__ rowidx,
    float* __restrict__ outf)
{
  int t = blockIdx.x;
  int c = threadIdx.x * 8;
  int r0 = rowidx[t*2], r1 = rowidx[t*2+1];
  const float4* a0 = reinterpret_cast<const float4*>(ydn + (size_t)r0 * HDIM + c);
  const float4* a1 = reinterpret_cast<const float4*>(ydn + (size_t)r1 * HDIM + c);
  float4* o = reinterpret_cast<float4*>(outf + (size_t)t * HDIM + c);
  float4 x0 = a0[0], x1 = a0[1], y0 = a1[0], y1 = a1[1];
  float4 o0 = o[0], o1 = o[1];
  o0.x += x0.x + y0.x; o0.y += x0.y + y0.y; o0.z += x0.z + y0.z; o0.w += x0.w + y0.w;
  o1.x += x1.x + y1.x; o1.y += x1.y + y1.y; o1.z += x1.z + y1.z; o1.w += x1.w + y1.w;
  o[0] = o0; o[1] = o1;
}

extern "C" void kernel_launch(void* const* d_in, const int* in_sizes, int n_in,
                              void* d_out, int out_size, void* d_ws, size_t ws_size,
                              hipStream_t stream) {
  const float* x      = (const float*)d_in[0];
  const float* rw     = (const float*)d_in[1];
  const float* w_gate = (const float*)d_in[2];
  const float* w_up   = (const float*)d_in[3];
  const float* w_down = (const float*)d_in[4];
  const float* sw_g   = (const float*)d_in[5];
  const float* sw_u   = (const float*)d_in[6];
  const float* sw_d   = (const float*)d_in[7];
  float* out_final  = (float*)d_out;                      // [T][H]
  float* out_logits = out_final + (size_t)T_TOK * HDIM;   // [T][E]

  char* ws = (char*)d_ws;
  int*   selk     = (int*)(ws + 0);
  float* cwk      = (float*)(ws + 8192);
  int*   rowidx   = (int*)(ws + 16384);
  int*   tokrow   = (int*)(ws + 24576);
  float* rowwgt   = (float*)(ws + 40960);
  int*   tile_tab = (int*)(ws + 57344);
  unsigned short* xg  = (unsigned short*)(ws + 65536);
  unsigned short* hg  = (unsigned short*)(ws + 65536 + 16777216);
  unsigned short* hsh = (unsigned short*)(ws + 65536 + 16777216 + 8650752);
  float* ydn = (float*)(ws + 65536 + 16777216 + 8650752 + 5767168);

  router_kernel<<<T_TOK, 256, 0, stream>>>(x, rw, out_logits, selk, cwk);
  plan_kernel<<<1, 512, 0, stream>>>(selk, cwk, rowidx, tokrow, rowwgt, tile_tab);
  gather_kernel<<<ROWS_ALL, 256, 0, stream>>>(x, tokrow, xg);
  gu_kernel<<<1760, 256, 0, stream>>>(
      xg, w_gate, w_up, sw_g, sw_u, rowwgt, tile_tab, hg, hsh);
  dn_kernel<<<2048, 256, 0, stream>>>(
      hg, hsh, w_down, sw_d, tile_tab, ydn, out_final);
  combine_kernel<<<T_TOK, 256, 0, stream>>>(ydn, rowidx, out_final);
}

// Round 6
// 311.801 us; speedup vs baseline: 1.7087x; 1.7087x over previous
//
#include <hip/hip_runtime.h>
#include <hip/hip_bf16.h>
#include <math.h>

#define T_TOK 1024
#define HDIM  2048
#define NEXP  8
#define IDIM  1408
#define ISH   2816
#define ROW_CAP 3072
#define ROWS_ALL 4096
#define MOE_TILES 24
#define NT_TOT 32

typedef __attribute__((ext_vector_type(8))) short bf16x8;
typedef __attribute__((ext_vector_type(4))) float f32x4;

static __device__ __forceinline__ unsigned short f2bf(float f) {
  __hip_bfloat16 h = __float2bfloat16(f);   // RTNE
  return __builtin_bit_cast(unsigned short, h);
}

// ---------------- router ----------------
__global__ __launch_bounds__(256) void router_kernel(
    const float* __restrict__ x, const float* __restrict__ rw,
    float* __restrict__ logits_out, int* __restrict__ selk, float* __restrict__ cwk)
{
  int t = blockIdx.x;
  int tid = threadIdx.x;
  float part[NEXP];
  const float* xr = x + (size_t)t * HDIM + tid * 8;
  float4 xa = *reinterpret_cast<const float4*>(xr);
  float4 xb = *reinterpret_cast<const float4*>(xr + 4);
  for (int e = 0; e < NEXP; ++e) {
    const float* wp = rw + (size_t)e * HDIM + tid * 8;
    float4 wa = *reinterpret_cast<const float4*>(wp);
    float4 wb = *reinterpret_cast<const float4*>(wp + 4);
    part[e] = xa.x*wa.x + xa.y*wa.y + xa.z*wa.z + xa.w*wa.w
            + xb.x*wb.x + xb.y*wb.y + xb.z*wb.z + xb.w*wb.w;
  }
  for (int e = 0; e < NEXP; ++e)
    for (int off = 32; off; off >>= 1)
      part[e] += __shfl_xor(part[e], off, 64);
  __shared__ float sums[4][NEXP];
  int wid = tid >> 6, lane = tid & 63;
  if (lane == 0) for (int e = 0; e < NEXP; ++e) sums[wid][e] = part[e];
  __syncthreads();
  if (tid == 0) {
    float lg[NEXP];
    for (int e = 0; e < NEXP; ++e) lg[e] = sums[0][e] + sums[1][e] + sums[2][e] + sums[3][e];
    float mx = lg[0];
    for (int e = 1; e < NEXP; ++e) mx = fmaxf(mx, lg[e]);
    float p[NEXP], s = 0.f;
    for (int e = 0; e < NEXP; ++e) { p[e] = expf(lg[e] - mx); s += p[e]; }
    for (int e = 0; e < NEXP; ++e) p[e] /= s;
    int i1 = 0;
    for (int e = 1; e < NEXP; ++e) if (lg[e] > lg[i1]) i1 = e;
    int i2 = -1;
    for (int e = 0; e < NEXP; ++e) { if (e == i1) continue; if (i2 < 0 || lg[e] > lg[i2]) i2 = e; }
    float denom = p[i1] + p[i2] + 1e-6f;
    selk[t*2] = i1; selk[t*2+1] = i2;
    cwk[t*2] = p[i1] / denom; cwk[t*2+1] = p[i2] / denom;
    for (int e = 0; e < NEXP; ++e) logits_out[t * NEXP + e] = lg[e];
  }
}

// ---------------- plan ----------------
__global__ __launch_bounds__(512) void plan_kernel(
    const int* __restrict__ selk, const float* __restrict__ cwk,
    int* __restrict__ rowidx, int* __restrict__ tok_of_row,
    float* __restrict__ rowwgt, int* __restrict__ tile_tab)
{
  __shared__ int cnt[NEXP];
  __shared__ int seg[NEXP];
  int tid = threadIdx.x;
  int w = tid >> 6, lane = tid & 63;
  for (int i = tid; i < ROW_CAP; i += 512) { tok_of_row[i] = -1; rowwgt[i] = 0.f; }
  for (int i = tid; i < T_TOK; i += 512) { tok_of_row[ROW_CAP + i] = i; rowwgt[ROW_CAP + i] = 1.f; }
  int total = 0;
  for (int base = 0; base < 2 * T_TOK; base += 64) {
    unsigned long long m = __ballot(selk[base + lane] == w);
    total += __popcll(m);
  }
  if (lane == 0) cnt[w] = total;
  __syncthreads();
  if (tid == 0) {
    int s = 0;
    for (int e = 0; e < NEXP; ++e) { seg[e] = s; s += (cnt[e] + 127) & ~127; }
  }
  __syncthreads();
  int run = seg[w];
  for (int base = 0; base < 2 * T_TOK; base += 64) {
    int i = base + lane;
    bool f = selk[i] == w;
    unsigned long long m = __ballot(f);
    if (f) {
      int r = run + __popcll(m & ((1ull << lane) - 1ull));
      rowidx[i] = r;
      tok_of_row[r] = i >> 1;
      rowwgt[r] = cwk[i];
    }
    run += __popcll(m);
  }
  __syncthreads();
  if (tid < NT_TOT) {
    int e = -1, valid = 0;
    if (tid < MOE_TILES) {
      int base = tid * 128;
      for (int k = 0; k < NEXP; ++k) {
        int s0 = seg[k], s1 = s0 + ((cnt[k] + 127) & ~127);
        if (base >= s0 && base < s1) {
          e = k;
          valid = cnt[k] - (base - s0);
          if (valid > 128) valid = 128;
          if (valid < 0) valid = 0;
        }
      }
    } else { e = 0; valid = 128; }
    tile_tab[tid*2] = e;
    tile_tab[tid*2+1] = valid;
  }
}

// ---------------- gather ----------------
__global__ __launch_bounds__(256) void gather_kernel(
    const float* __restrict__ x, const int* __restrict__ tok_of_row,
    unsigned short* __restrict__ xg)
{
  int r = blockIdx.x;
  int tid = threadIdx.x;
  int tok = tok_of_row[r];
  unsigned short* dst = xg + (size_t)r * HDIM + tid * 8;
  union { unsigned short us[8]; uint4 q; } p;
  if (tok < 0) {
    p.q = uint4{0, 0, 0, 0};
  } else {
    const float* src = x + (size_t)tok * HDIM + tid * 8;
    float4 a = *reinterpret_cast<const float4*>(src);
    float4 b = *reinterpret_cast<const float4*>(src + 4);
    p.us[0]=f2bf(a.x); p.us[1]=f2bf(a.y); p.us[2]=f2bf(a.z); p.us[3]=f2bf(a.w);
    p.us[4]=f2bf(b.x); p.us[5]=f2bf(b.y); p.us[6]=f2bf(b.z); p.us[7]=f2bf(b.w);
  }
  *reinterpret_cast<uint4*>(dst) = p.q;
}

// ---- B tile helpers ----
static __device__ __forceinline__ void bwrite(
    unsigned short (*Bs)[72], int brow, int bc, const float4* v)
{
  union { unsigned short us[8]; uint4 q; } a, b;
  a.us[0]=f2bf(v[0].x); a.us[1]=f2bf(v[0].y); a.us[2]=f2bf(v[0].z); a.us[3]=f2bf(v[0].w);
  a.us[4]=f2bf(v[1].x); a.us[5]=f2bf(v[1].y); a.us[6]=f2bf(v[1].z); a.us[7]=f2bf(v[1].w);
  b.us[0]=f2bf(v[2].x); b.us[1]=f2bf(v[2].y); b.us[2]=f2bf(v[2].z); b.us[3]=f2bf(v[2].w);
  b.us[4]=f2bf(v[3].x); b.us[5]=f2bf(v[3].y); b.us[6]=f2bf(v[3].z); b.us[7]=f2bf(v[3].w);
  *reinterpret_cast<uint4*>(&Bs[brow][bc]) = a.q;
  *reinterpret_cast<uint4*>(&Bs[brow][bc + 8]) = b.q;
}

static __device__ __forceinline__ void bload(const float* __restrict__ src, float4* v)
{
  v[0] = *reinterpret_cast<const float4*>(src);
  v[1] = *reinterpret_cast<const float4*>(src + 4);
  v[2] = *reinterpret_cast<const float4*>(src + 8);
  v[3] = *reinterpret_cast<const float4*>(src + 12);
}

// ---- A stage: global_load_lds, linear LDS dest, XOR-swizzled global source ----
static __device__ __forceinline__ void stage_a(
    const unsigned short* __restrict__ abase, size_t lda, int k0,
    unsigned short* As, int wid, int lane)
{
  #pragma unroll
  for (int j = 0; j < 2; ++j) {
    int row = j * 64 + wid * 8 + (lane >> 3);
    int col = ((lane & 7) ^ (row & 7)) << 3;
    const unsigned short* src = abase + (size_t)row * lda + k0 + col;
    unsigned short* dst = &As[(j * 64 + wid * 8) * 64];   // wave-uniform
    __builtin_amdgcn_global_load_lds(
        (const __attribute__((address_space(1))) void*)src,
        (__attribute__((address_space(3))) void*)dst, 16, 0, 0);
  }
}

// ---------------- grouped gate+up SwiGLU (R2 structure + swizzle + B-prefetch) ----------------
__global__ __launch_bounds__(512) void gu_kernel(
    const unsigned short* __restrict__ xg,
    const float* __restrict__ w_gate, const float* __restrict__ w_up,
    const float* __restrict__ sw_gate, const float* __restrict__ sw_up,
    const float* __restrict__ rowwgt, const int* __restrict__ tile_tab,
    unsigned short* __restrict__ hg, unsigned short* __restrict__ hsh)
{
  // bijective XCD chunk swizzle (nwg = 440 = 8*55), mt-fastest
  int bid = blockIdx.x;
  int lb = (bid & 7) * 55 + (bid >> 3);
  int mt, nt;
  if (lb < MOE_TILES * 11) { mt = lb % MOE_TILES; nt = lb / MOE_TILES; }
  else { int s = lb - MOE_TILES * 11; mt = MOE_TILES + (s & 7); nt = s >> 3; }

  int e = tile_tab[mt*2], valid = tile_tab[mt*2+1];
  if (valid <= 0) return;
  bool sh = mt >= MOE_TILES;
  int m0 = mt * 128, n0 = nt * 128;
  const float *wg, *wu; unsigned short* hout; int ldo;
  if (sh) { wg = sw_gate; wu = sw_up; hout = hsh + (size_t)(m0 - ROW_CAP) * ISH; ldo = ISH; }
  else {
    size_t wo = (size_t)e * IDIM * HDIM;
    wg = w_gate + wo; wu = w_up + wo;
    hout = hg + (size_t)m0 * IDIM; ldo = IDIM;
  }

  __shared__ unsigned short As[128 * 64];
  __shared__ unsigned short BgS[128][72];
  __shared__ unsigned short BuS[128][72];

  int tid = threadIdx.x, wid = tid >> 6, lane = tid & 63;
  int wr = wid >> 2, wc = wid & 3;
  int fr = lane & 15, fq8 = (lane >> 4) << 3;

  f32x4 accg[4][2] = {{}};
  f32x4 accu[4][2] = {{}};

  int brow = tid >> 2, bc = (tid & 3) << 4;
  const float* gsrc = wg + (size_t)(n0 + brow) * HDIM + bc;
  const float* usrc = wu + (size_t)(n0 + brow) * HDIM + bc;
  const unsigned short* abase = xg + (size_t)m0 * HDIM;

  float4 pg[4], pu[4];
  bload(gsrc, pg); bload(usrc, pu);   // tile 0 B regs

  const int NK = HDIM / 64;
  for (int t = 0; t < NK; ++t) {
    int k1 = (t + 1 < NK) ? (t + 1) * 64 : 0;
    stage_a(abase, HDIM, t * 64, As, wid, lane);   // A(t) async into LDS
    bwrite(BgS, brow, bc, pg);                     // B(t) regs -> LDS (waits own loads)
    bwrite(BuS, brow, bc, pu);
    __syncthreads();                               // A(t)+B(t) visible
    bload(gsrc + k1, pg);                          // B(t+1) issue — overlaps MFMA
    bload(usrc + k1, pu);
    #pragma unroll
    for (int kk = 0; kk < 64; kk += 32) {
      bf16x8 a[4], bg[2], bu[2];
      #pragma unroll
      for (int m = 0; m < 4; ++m) {
        int row = wr * 64 + m * 16 + fr;
        a[m] = *reinterpret_cast<const bf16x8*>(&As[row * 64 + ((kk + fq8) ^ ((row & 7) << 3))]);
      }
      #pragma unroll
      for (int n = 0; n < 2; ++n) {
        bg[n] = *reinterpret_cast<const bf16x8*>(&BgS[wc * 32 + n * 16 + fr][kk + fq8]);
        bu[n] = *reinterpret_cast<const bf16x8*>(&BuS[wc * 32 + n * 16 + fr][kk + fq8]);
      }
      #pragma unroll
      for (int m = 0; m < 4; ++m)
        #pragma unroll
        for (int n = 0; n < 2; ++n) {
          accg[m][n] = __builtin_amdgcn_mfma_f32_16x16x32_bf16(a[m], bg[n], accg[m][n], 0, 0, 0);
          accu[m][n] = __builtin_amdgcn_mfma_f32_16x16x32_bf16(a[m], bu[n], accu[m][n], 0, 0, 0);
        }
    }
    __syncthreads();                               // reads of As/B done; drain
  }

  int fq = lane >> 4;
  #pragma unroll
  for (int m = 0; m < 4; ++m)
    #pragma unroll
    for (int j = 0; j < 4; ++j) {
      int grow = wr * 64 + m * 16 + fq * 4 + j;
      float wv = rowwgt[m0 + grow];
      #pragma unroll
      for (int n = 0; n < 2; ++n) {
        float g = accg[m][n][j], u = accu[m][n][j];
        float hv = g / (1.f + __expf(-g)) * u * wv;
        hout[(size_t)grow * ldo + n0 + wc * 32 + n * 16 + fr] = f2bf(hv);
      }
    }
}

// ---------------- grouped down-proj (R2 structure + swizzle + B-prefetch) ----------------
__global__ __launch_bounds__(512) void dn_kernel(
    const unsigned short* __restrict__ hg, const unsigned short* __restrict__ hsh,
    const float* __restrict__ w_down, const float* __restrict__ sw_down,
    const int* __restrict__ tile_tab,
    float* __restrict__ ydn, float* __restrict__ outf)
{
  // bijective XCD chunk swizzle (nwg = 512 = 8*64), mt-fastest
  int bid = blockIdx.x;
  int lb = (bid & 7) * 64 + (bid >> 3);
  int mt, nt;
  if (lb < MOE_TILES * 16) { mt = lb % MOE_TILES; nt = lb / MOE_TILES; }
  else { int s = lb - MOE_TILES * 16; mt = MOE_TILES + (s & 7); nt = s >> 3; }

  int e = tile_tab[mt*2], valid = tile_tab[mt*2+1];
  if (valid <= 0) return;
  bool sh = mt >= MOE_TILES;
  int m0 = mt * 128, n0 = nt * 128;
  const unsigned short* abase; const float* bbase; int K; float* obase;
  if (sh) { abase = hsh + (size_t)(m0 - ROW_CAP) * ISH; K = ISH; bbase = sw_down; obase = outf + (size_t)(m0 - ROW_CAP) * HDIM; }
  else { abase = hg + (size_t)m0 * IDIM; K = IDIM; bbase = w_down + (size_t)e * HDIM * IDIM; obase = ydn + (size_t)m0 * HDIM; }

  __shared__ unsigned short As[128 * 64];
  __shared__ unsigned short BsS[128][72];

  int tid = threadIdx.x, wid = tid >> 6, lane = tid & 63;
  int wr = wid >> 2, wc = wid & 3;
  int fr = lane & 15, fq8 = (lane >> 4) << 3;

  f32x4 acc[4][2] = {{}};

  int brow = tid >> 2, bc = (tid & 3) << 4;
  const float* bsrc = bbase + (size_t)(n0 + brow) * K + bc;

  float4 pb[4];
  bload(bsrc, pb);

  const int NK = K / 64;
  for (int t = 0; t < NK; ++t) {
    int k1 = (t + 1 < NK) ? (t + 1) * 64 : 0;
    stage_a(abase, K, t * 64, As, wid, lane);
    bwrite(BsS, brow, bc, pb);
    __syncthreads();
    bload(bsrc + k1, pb);
    #pragma unroll
    for (int kk = 0; kk < 64; kk += 32) {
      bf16x8 a[4], b[2];
      #pragma unroll
      for (int m = 0; m < 4; ++m) {
        int row = wr * 64 + m * 16 + fr;
        a[m] = *reinterpret_cast<const bf16x8*>(&As[row * 64 + ((kk + fq8) ^ ((row & 7) << 3))]);
      }
      #pragma unroll
      for (int n = 0; n < 2; ++n)
        b[n] = *reinterpret_cast<const bf16x8*>(&BsS[wc * 32 + n * 16 + fr][kk + fq8]);
      #pragma unroll
      for (int m = 0; m < 4; ++m)
        #pragma unroll
        for (int n = 0; n < 2; ++n)
          acc[m][n] = __builtin_amdgcn_mfma_f32_16x16x32_bf16(a[m], b[n], acc[m][n], 0, 0, 0);
    }
    __syncthreads();
  }
  int fq = lane >> 4;
  #pragma unroll
  for (int m = 0; m < 4; ++m)
    #pragma unroll
    for (int j = 0; j < 4; ++j) {
      int grow = wr * 64 + m * 16 + fq * 4 + j;
      #pragma unroll
      for (int n = 0; n < 2; ++n)
        obase[(size_t)grow * HDIM + n0 + wc * 32 + n * 16 + fr] = acc[m][n][j];
    }
}

// ---------------- combine ----------------
__global__ __launch_bounds__(256) void combine_kernel(
    const float* __restrict__ ydn, const int* __restrict__ rowidx,
    float* __restrict__ outf)
{
  int t = blockIdx.x;
  int c = threadIdx.x * 8;
  int r0 = rowidx[t*2], r1 = rowidx[t*2+1];
  const float4* a0 = reinterpret_cast<const float4*>(ydn + (size_t)r0 * HDIM + c);
  const float4* a1 = reinterpret_cast<const float4*>(ydn + (size_t)r1 * HDIM + c);
  float4* o = reinterpret_cast<float4*>(outf + (size_t)t * HDIM + c);
  float4 x0 = a0[0], x1 = a0[1], y0 = a1[0], y1 = a1[1];
  float4 o0 = o[0], o1 = o[1];
  o0.x += x0.x + y0.x; o0.y += x0.y + y0.y; o0.z += x0.z + y0.z; o0.w += x0.w + y0.w;
  o1.x += x1.x + y1.x; o1.y += x1.y + y1.y; o1.z += x1.z + y1.z; o1.w += x1.w + y1.w;
  o[0] = o0; o[1] = o1;
}

extern "C" void kernel_launch(void* const* d_in, const int* in_sizes, int n_in,
                              void* d_out, int out_size, void* d_ws, size_t ws_size,
                              hipStream_t stream) {
  const float* x      = (const float*)d_in[0];
  const float* rw     = (const float*)d_in[1];
  const float* w_gate = (const float*)d_in[2];
  const float* w_up   = (const float*)d_in[3];
  const float* w_down = (const float*)d_in[4];
  const float* sw_g   = (const float*)d_in[5];
  const float* sw_u   = (const float*)d_in[6];
  const float* sw_d   = (const float*)d_in[7];
  float* out_final  = (float*)d_out;                      // [T][H]
  float* out_logits = out_final + (size_t)T_TOK * HDIM;   // [T][E]

  char* ws = (char*)d_ws;
  int*   selk     = (int*)(ws + 0);
  float* cwk      = (float*)(ws + 8192);
  int*   rowidx   = (int*)(ws + 16384);
  int*   tokrow   = (int*)(ws + 24576);
  float* rowwgt   = (float*)(ws + 40960);
  int*   tile_tab = (int*)(ws + 57344);
  unsigned short* xg  = (unsigned short*)(ws + 65536);
  unsigned short* hg  = (unsigned short*)(ws + 65536 + 16777216);
  unsigned short* hsh = (unsigned short*)(ws + 65536 + 16777216 + 8650752);
  float* ydn = (float*)(ws + 65536 + 16777216 + 8650752 + 5767168);

  router_kernel<<<T_TOK, 256, 0, stream>>>(x, rw, out_logits, selk, cwk);
  plan_kernel<<<1, 512, 0, stream>>>(selk, cwk, rowidx, tokrow, rowwgt, tile_tab);
  gather_kernel<<<ROWS_ALL, 256, 0, stream>>>(x, tokrow, xg);
  gu_kernel<<<440, 512, 0, stream>>>(
      xg, w_gate, w_up, sw_g, sw_u, rowwgt, tile_tab, hg, hsh);
  dn_kernel<<<512, 512, 0, stream>>>(
      hg, hsh, w_down, sw_d, tile_tab, ydn, out_final);
  combine_kernel<<<T_TOK, 256, 0, stream>>>(ydn, rowidx, out_final);
}

// Round 7
// 257.184 us; speedup vs baseline: 2.0715x; 1.2124x over previous
//
#include <hip/hip_runtime.h>
#include <hip/hip_bf16.h>
#include <math.h>

#define T_TOK 1024
#define HDIM  2048
#define NEXP  8
#define IDIM  1408
#define ISH   2816
#define ROW_CAP 3072
#define ROWS_ALL 4096
#define MOE_TILES 24
#define NT_TOT 32

typedef __attribute__((ext_vector_type(8))) short bf16x8;
typedef __attribute__((ext_vector_type(4))) float f32x4;

static __device__ __forceinline__ unsigned short f2bf(float f) {
  __hip_bfloat16 h = __float2bfloat16(f);   // RTNE
  return __builtin_bit_cast(unsigned short, h);
}

// ---------------- router ----------------
__global__ __launch_bounds__(256) void router_kernel(
    const float* __restrict__ x, const float* __restrict__ rw,
    float* __restrict__ logits_out, int* __restrict__ selk, float* __restrict__ cwk)
{
  int t = blockIdx.x;
  int tid = threadIdx.x;
  float part[NEXP];
  const float* xr = x + (size_t)t * HDIM + tid * 8;
  float4 xa = *reinterpret_cast<const float4*>(xr);
  float4 xb = *reinterpret_cast<const float4*>(xr + 4);
  for (int e = 0; e < NEXP; ++e) {
    const float* wp = rw + (size_t)e * HDIM + tid * 8;
    float4 wa = *reinterpret_cast<const float4*>(wp);
    float4 wb = *reinterpret_cast<const float4*>(wp + 4);
    part[e] = xa.x*wa.x + xa.y*wa.y + xa.z*wa.z + xa.w*wa.w
            + xb.x*wb.x + xb.y*wb.y + xb.z*wb.z + xb.w*wb.w;
  }
  for (int e = 0; e < NEXP; ++e)
    for (int off = 32; off; off >>= 1)
      part[e] += __shfl_xor(part[e], off, 64);
  __shared__ float sums[4][NEXP];
  int wid = tid >> 6, lane = tid & 63;
  if (lane == 0) for (int e = 0; e < NEXP; ++e) sums[wid][e] = part[e];
  __syncthreads();
  if (tid == 0) {
    float lg[NEXP];
    for (int e = 0; e < NEXP; ++e) lg[e] = sums[0][e] + sums[1][e] + sums[2][e] + sums[3][e];
    float mx = lg[0];
    for (int e = 1; e < NEXP; ++e) mx = fmaxf(mx, lg[e]);
    float p[NEXP], s = 0.f;
    for (int e = 0; e < NEXP; ++e) { p[e] = expf(lg[e] - mx); s += p[e]; }
    for (int e = 0; e < NEXP; ++e) p[e] /= s;
    int i1 = 0;
    for (int e = 1; e < NEXP; ++e) if (lg[e] > lg[i1]) i1 = e;
    int i2 = -1;
    for (int e = 0; e < NEXP; ++e) { if (e == i1) continue; if (i2 < 0 || lg[e] > lg[i2]) i2 = e; }
    float denom = p[i1] + p[i2] + 1e-6f;
    selk[t*2] = i1; selk[t*2+1] = i2;
    cwk[t*2] = p[i1] / denom; cwk[t*2+1] = p[i2] / denom;
    for (int e = 0; e < NEXP; ++e) logits_out[t * NEXP + e] = lg[e];
  }
}

// ---------------- plan ----------------
__global__ __launch_bounds__(512) void plan_kernel(
    const int* __restrict__ selk, const float* __restrict__ cwk,
    int* __restrict__ rowidx, int* __restrict__ tok_of_row,
    float* __restrict__ rowwgt, int* __restrict__ tile_tab)
{
  __shared__ int cnt[NEXP];
  __shared__ int seg[NEXP];
  int tid = threadIdx.x;
  int w = tid >> 6, lane = tid & 63;
  for (int i = tid; i < ROW_CAP; i += 512) { tok_of_row[i] = -1; rowwgt[i] = 0.f; }
  for (int i = tid; i < T_TOK; i += 512) { tok_of_row[ROW_CAP + i] = i; rowwgt[ROW_CAP + i] = 1.f; }
  int total = 0;
  for (int base = 0; base < 2 * T_TOK; base += 64) {
    unsigned long long m = __ballot(selk[base + lane] == w);
    total += __popcll(m);
  }
  if (lane == 0) cnt[w] = total;
  __syncthreads();
  if (tid == 0) {
    int s = 0;
    for (int e = 0; e < NEXP; ++e) { seg[e] = s; s += (cnt[e] + 127) & ~127; }
  }
  __syncthreads();
  int run = seg[w];
  for (int base = 0; base < 2 * T_TOK; base += 64) {
    int i = base + lane;
    bool f = selk[i] == w;
    unsigned long long m = __ballot(f);
    if (f) {
      int r = run + __popcll(m & ((1ull << lane) - 1ull));
      rowidx[i] = r;
      tok_of_row[r] = i >> 1;
      rowwgt[r] = cwk[i];
    }
    run += __popcll(m);
  }
  __syncthreads();
  if (tid < NT_TOT) {
    int e = -1, valid = 0;
    if (tid < MOE_TILES) {
      int base = tid * 128;
      for (int k = 0; k < NEXP; ++k) {
        int s0 = seg[k], s1 = s0 + ((cnt[k] + 127) & ~127);
        if (base >= s0 && base < s1) {
          e = k;
          valid = cnt[k] - (base - s0);
          if (valid > 128) valid = 128;
          if (valid < 0) valid = 0;
        }
      }
    } else { e = 0; valid = 128; }
    tile_tab[tid*2] = e;
    tile_tab[tid*2+1] = valid;
  }
}

// ---------------- gather ----------------
__global__ __launch_bounds__(256) void gather_kernel(
    const float* __restrict__ x, const int* __restrict__ tok_of_row,
    unsigned short* __restrict__ xg)
{
  int r = blockIdx.x;
  int tid = threadIdx.x;
  int tok = tok_of_row[r];
  unsigned short* dst = xg + (size_t)r * HDIM + tid * 8;
  union { unsigned short us[8]; uint4 q; } p;
  if (tok < 0) {
    p.q = uint4{0, 0, 0, 0};
  } else {
    const float* src = x + (size_t)tok * HDIM + tid * 8;
    float4 a = *reinterpret_cast<const float4*>(src);
    float4 b = *reinterpret_cast<const float4*>(src + 4);
    p.us[0]=f2bf(a.x); p.us[1]=f2bf(a.y); p.us[2]=f2bf(a.z); p.us[3]=f2bf(a.w);
    p.us[4]=f2bf(b.x); p.us[5]=f2bf(b.y); p.us[6]=f2bf(b.z); p.us[7]=f2bf(b.w);
  }
  *reinterpret_cast<uint4*>(dst) = p.q;
}

// ---- B stage: 8 fp32 -> 8 bf16 per thread into padded [64][72] tile ----
static __device__ __forceinline__ void stage_b64(
    const float* __restrict__ src, unsigned short (*Bs)[72], int brow, int bc)
{
  float4 v0 = *reinterpret_cast<const float4*>(src);
  float4 v1 = *reinterpret_cast<const float4*>(src + 4);
  union { unsigned short us[8]; uint4 q; } a;
  a.us[0]=f2bf(v0.x); a.us[1]=f2bf(v0.y); a.us[2]=f2bf(v0.z); a.us[3]=f2bf(v0.w);
  a.us[4]=f2bf(v1.x); a.us[5]=f2bf(v1.y); a.us[6]=f2bf(v1.z); a.us[7]=f2bf(v1.w);
  *reinterpret_cast<uint4*>(&Bs[brow][bc]) = a.q;
}

// ---- A stage: global_load_lds, linear LDS dest, XOR-swizzled global source ----
static __device__ __forceinline__ void stage_a(
    const unsigned short* __restrict__ abase, size_t lda, int k0,
    unsigned short* As, int wid, int lane)
{
  #pragma unroll
  for (int j = 0; j < 2; ++j) {
    int row = j * 64 + wid * 8 + (lane >> 3);
    int col = ((lane & 7) ^ (row & 7)) << 3;
    const unsigned short* src = abase + (size_t)row * lda + k0 + col;
    unsigned short* dst = &As[(j * 64 + wid * 8) * 64];   // wave-uniform
    __builtin_amdgcn_global_load_lds(
        (const __attribute__((address_space(1))) void*)src,
        (__attribute__((address_space(3))) void*)dst, 16, 0, 0);
  }
}

// ---------------- grouped gate+up SwiGLU: BM=128, BN=64, 512 thr ----------------
__global__ __launch_bounds__(512, 4) void gu_kernel(
    const unsigned short* __restrict__ xg,
    const float* __restrict__ w_gate, const float* __restrict__ w_up,
    const float* __restrict__ sw_gate, const float* __restrict__ sw_up,
    const float* __restrict__ rowwgt, const int* __restrict__ tile_tab,
    unsigned short* __restrict__ hg, unsigned short* __restrict__ hsh)
{
  int mt = blockIdx.y, nt = blockIdx.x;
  int e = tile_tab[mt*2], valid = tile_tab[mt*2+1];
  bool sh = mt >= MOE_TILES;
  int ntiles = sh ? (ISH / 64) : (IDIM / 64);
  if (valid <= 0 || nt >= ntiles) return;
  int m0 = mt * 128, n0 = nt * 64;
  const float *wg, *wu; unsigned short* hout; int ldo;
  if (sh) { wg = sw_gate; wu = sw_up; hout = hsh + (size_t)(m0 - ROW_CAP) * ISH; ldo = ISH; }
  else {
    size_t wo = (size_t)e * IDIM * HDIM;
    wg = w_gate + wo; wu = w_up + wo;
    hout = hg + (size_t)m0 * IDIM; ldo = IDIM;
  }

  __shared__ unsigned short As[128 * 64];       // 16 KB
  __shared__ unsigned short BgS[64][72];        // 9.2 KB
  __shared__ unsigned short BuS[64][72];        // 9.2 KB

  int tid = threadIdx.x, wid = tid >> 6, lane = tid & 63;
  int wr = wid >> 1, wc = wid & 1;              // 4 x 2 waves, 32x32 wave tile
  int fr = lane & 15, fq8 = (lane >> 4) << 3;

  f32x4 accg[2][2] = {{}};
  f32x4 accu[2][2] = {{}};

  int brow = tid >> 3, bc = (tid & 7) << 3;     // 8 thr/row, 8 floats each
  const float* gsrc = wg + (size_t)(n0 + brow) * HDIM + bc;
  const float* usrc = wu + (size_t)(n0 + brow) * HDIM + bc;
  const unsigned short* abase = xg + (size_t)m0 * HDIM;

  for (int k0 = 0; k0 < HDIM; k0 += 64) {
    stage_a(abase, HDIM, k0, As, wid, lane);
    stage_b64(gsrc + k0, BgS, brow, bc);
    stage_b64(usrc + k0, BuS, brow, bc);
    __syncthreads();
    #pragma unroll
    for (int kk = 0; kk < 64; kk += 32) {
      bf16x8 a[2], bg[2], bu[2];
      #pragma unroll
      for (int m = 0; m < 2; ++m) {
        int row = wr * 32 + m * 16 + fr;
        a[m] = *reinterpret_cast<const bf16x8*>(&As[row * 64 + ((kk + fq8) ^ ((row & 7) << 3))]);
      }
      #pragma unroll
      for (int n = 0; n < 2; ++n) {
        bg[n] = *reinterpret_cast<const bf16x8*>(&BgS[wc * 32 + n * 16 + fr][kk + fq8]);
        bu[n] = *reinterpret_cast<const bf16x8*>(&BuS[wc * 32 + n * 16 + fr][kk + fq8]);
      }
      #pragma unroll
      for (int m = 0; m < 2; ++m)
        #pragma unroll
        for (int n = 0; n < 2; ++n) {
          accg[m][n] = __builtin_amdgcn_mfma_f32_16x16x32_bf16(a[m], bg[n], accg[m][n], 0, 0, 0);
          accu[m][n] = __builtin_amdgcn_mfma_f32_16x16x32_bf16(a[m], bu[n], accu[m][n], 0, 0, 0);
        }
    }
    __syncthreads();
  }

  int fq = lane >> 4;
  #pragma unroll
  for (int m = 0; m < 2; ++m)
    #pragma unroll
    for (int j = 0; j < 4; ++j) {
      int grow = wr * 32 + m * 16 + fq * 4 + j;
      float wv = rowwgt[m0 + grow];
      #pragma unroll
      for (int n = 0; n < 2; ++n) {
        float g = accg[m][n][j], u = accu[m][n][j];
        float hv = g / (1.f + __expf(-g)) * u * wv;
        hout[(size_t)grow * ldo + n0 + wc * 32 + n * 16 + fr] = f2bf(hv);
      }
    }
}

// ---------------- grouped down-proj: BM=128, BN=64, 512 thr ----------------
__global__ __launch_bounds__(512, 4) void dn_kernel(
    const unsigned short* __restrict__ hg, const unsigned short* __restrict__ hsh,
    const float* __restrict__ w_down, const float* __restrict__ sw_down,
    const int* __restrict__ tile_tab,
    float* __restrict__ ydn, float* __restrict__ outf)
{
  int mt = blockIdx.y, nt = blockIdx.x;
  int e = tile_tab[mt*2], valid = tile_tab[mt*2+1];
  if (valid <= 0) return;
  bool sh = mt >= MOE_TILES;
  int m0 = mt * 128, n0 = nt * 64;
  const unsigned short* abase; const float* bbase; int K; float* obase;
  if (sh) { abase = hsh + (size_t)(m0 - ROW_CAP) * ISH; K = ISH; bbase = sw_down; obase = outf + (size_t)(m0 - ROW_CAP) * HDIM; }
  else { abase = hg + (size_t)m0 * IDIM; K = IDIM; bbase = w_down + (size_t)e * HDIM * IDIM; obase = ydn + (size_t)m0 * HDIM; }

  __shared__ unsigned short As[128 * 64];       // 16 KB
  __shared__ unsigned short BsS[64][72];        // 9.2 KB

  int tid = threadIdx.x, wid = tid >> 6, lane = tid & 63;
  int wr = wid >> 1, wc = wid & 1;
  int fr = lane & 15, fq8 = (lane >> 4) << 3;

  f32x4 acc[2][2] = {{}};

  int brow = tid >> 3, bc = (tid & 7) << 3;
  const float* bsrc = bbase + (size_t)(n0 + brow) * K + bc;

  for (int k0 = 0; k0 < K; k0 += 64) {
    stage_a(abase, K, k0, As, wid, lane);
    stage_b64(bsrc + k0, BsS, brow, bc);
    __syncthreads();
    #pragma unroll
    for (int kk = 0; kk < 64; kk += 32) {
      bf16x8 a[2], b[2];
      #pragma unroll
      for (int m = 0; m < 2; ++m) {
        int row = wr * 32 + m * 16 + fr;
        a[m] = *reinterpret_cast<const bf16x8*>(&As[row * 64 + ((kk + fq8) ^ ((row & 7) << 3))]);
      }
      #pragma unroll
      for (int n = 0; n < 2; ++n)
        b[n] = *reinterpret_cast<const bf16x8*>(&BsS[wc * 32 + n * 16 + fr][kk + fq8]);
      #pragma unroll
      for (int m = 0; m < 2; ++m)
        #pragma unroll
        for (int n = 0; n < 2; ++n)
          acc[m][n] = __builtin_amdgcn_mfma_f32_16x16x32_bf16(a[m], b[n], acc[m][n], 0, 0, 0);
    }
    __syncthreads();
  }
  int fq = lane >> 4;
  #pragma unroll
  for (int m = 0; m < 2; ++m)
    #pragma unroll
    for (int j = 0; j < 4; ++j) {
      int grow = wr * 32 + m * 16 + fq * 4 + j;
      #pragma unroll
      for (int n = 0; n < 2; ++n)
        obase[(size_t)grow * HDIM + n0 + wc * 32 + n * 16 + fr] = acc[m][n][j];
    }
}

// ---------------- combine ----------------
__global__ __launch_bounds__(256) void combine_kernel(
    const float* __restrict__ ydn, const int* __restrict__ rowidx,
    float* __restrict__ outf)
{
  int t = blockIdx.x;
  int c = threadIdx.x * 8;
  int r0 = rowidx[t*2], r1 = rowidx[t*2+1];
  const float4* a0 = reinterpret_cast<const float4*>(ydn + (size_t)r0 * HDIM + c);
  const float4* a1 = reinterpret_cast<const float4*>(ydn + (size_t)r1 * HDIM + c);
  float4* o = reinterpret_cast<float4*>(outf + (size_t)t * HDIM + c);
  float4 x0 = a0[0], x1 = a0[1], y0 = a1[0], y1 = a1[1];
  float4 o0 = o[0], o1 = o[1];
  o0.x += x0.x + y0.x; o0.y += x0.y + y0.y; o0.z += x0.z + y0.z; o0.w += x0.w + y0.w;
  o1.x += x1.x + y1.x; o1.y += x1.y + y1.y; o1.z += x1.z + y1.z; o1.w += x1.w + y1.w;
  o[0] = o0; o[1] = o1;
}

extern "C" void kernel_launch(void* const* d_in, const int* in_sizes, int n_in,
                              void* d_out, int out_size, void* d_ws, size_t ws_size,
                              hipStream_t stream) {
  const float* x      = (const float*)d_in[0];
  const float* rw     = (const float*)d_in[1];
  const float* w_gate = (const float*)d_in[2];
  const float* w_up   = (const float*)d_in[3];
  const float* w_down = (const float*)d_in[4];
  const float* sw_g   = (const float*)d_in[5];
  const float* sw_u   = (const float*)d_in[6];
  const float* sw_d   = (const float*)d_in[7];
  float* out_final  = (float*)d_out;                      // [T][H]
  float* out_logits = out_final + (size_t)T_TOK * HDIM;   // [T][E]

  char* ws = (char*)d_ws;
  int*   selk     = (int*)(ws + 0);
  float* cwk      = (float*)(ws + 8192);
  int*   rowidx   = (int*)(ws + 16384);
  int*   tokrow   = (int*)(ws + 24576);
  float* rowwgt   = (float*)(ws + 40960);
  int*   tile_tab = (int*)(ws + 57344);
  unsigned short* xg  = (unsigned short*)(ws + 65536);
  unsigned short* hg  = (unsigned short*)(ws + 65536 + 16777216);
  unsigned short* hsh = (unsigned short*)(ws + 65536 + 16777216 + 8650752);
  float* ydn = (float*)(ws + 65536 + 16777216 + 8650752 + 5767168);

  router_kernel<<<T_TOK, 256, 0, stream>>>(x, rw, out_logits, selk, cwk);
  plan_kernel<<<1, 512, 0, stream>>>(selk, cwk, rowidx, tokrow, rowwgt, tile_tab);
  gather_kernel<<<ROWS_ALL, 256, 0, stream>>>(x, tokrow, xg);
  gu_kernel<<<dim3(ISH / 64, NT_TOT), 512, 0, stream>>>(
      xg, w_gate, w_up, sw_g, sw_u, rowwgt, tile_tab, hg, hsh);
  dn_kernel<<<dim3(HDIM / 64, NT_TOT), 512, 0, stream>>>(
      hg, hsh, w_down, sw_d, tile_tab, ydn, out_final);
  combine_kernel<<<T_TOK, 256, 0, stream>>>(ydn, rowidx, out_final);
}